// Round 12
// baseline (106.411 us; speedup 1.0000x reference)
//
#include <hip/hip_runtime.h>

#define N_NODES 100000
#define N_EDGES 1600000

// --- bucket-sort build parameters ---
#define SPAN 256
#define NB 391                        // ceil(100000/256)
#define NBLK_A 256
#define EPB (N_EDGES / NBLK_A)        // 6250

// --- legacy path parameters ---
#define SCAN_CHUNK 2048
#define SCAN_BLOCKS ((N_NODES + SCAN_CHUNK - 1) / SCAN_CHUNK)

typedef __attribute__((ext_vector_type(8))) short bf16x8;
typedef __attribute__((ext_vector_type(4))) float f32x4;

static __device__ __forceinline__ unsigned short f2bf(float f) {
    unsigned u = __float_as_uint(f);
    unsigned r = (u + 0x7FFF + ((u >> 16) & 1)) >> 16;   // RNE
    return (unsigned short)r;
}

// ===========================================================================
// Build: deterministic two-level bucket sort, no global atomics.
// ws (ints): offs[N] | M[NBLK_A*NB] | bcount[NB] | binned[E] | csr[E] | xb
// ===========================================================================

__global__ __launch_bounds__(512) void count_buckets(const int* __restrict__ ei,
                                                     int* __restrict__ M) {
    __shared__ int hist[NB];
    int tid = threadIdx.x;
    for (int i = tid; i < NB; i += 512) hist[i] = 0;
    __syncthreads();
    int e0 = blockIdx.x * EPB;
    for (int e = e0 + tid; e < e0 + EPB; e += 512)
        atomicAdd(&hist[ei[N_EDGES + e] >> 8], 1);
    __syncthreads();
    for (int i = tid; i < NB; i += 512) M[blockIdx.x * NB + i] = hist[i];
}

// One block per bucket: parallel LDS scan over the 256 per-block counts.
__global__ __launch_bounds__(256) void col_scan(int* __restrict__ M,
                                                int* __restrict__ bcount) {
    __shared__ int s[256];
    int b = blockIdx.x;          // bucket
    int t = threadIdx.x;         // source block
    int v = M[t * NB + b];
    s[t] = v;
    __syncthreads();
    for (int off = 1; off < 256; off <<= 1) {
        int u = (t >= off) ? s[t - off] : 0;
        __syncthreads();
        s[t] += u;
        __syncthreads();
    }
    M[t * NB + b] = s[t] - v;    // exclusive offset of block t within bucket b
    if (t == 255) bcount[b] = s[255];
}

__global__ __launch_bounds__(512) void bin_edges(const int* __restrict__ ei,
                                                 const int* __restrict__ M,
                                                 const int* __restrict__ bcount,
                                                 int* __restrict__ binned) {
    __shared__ int sb[512];
    __shared__ int sbase[NB];
    __shared__ int cur[NB];
    int tid = threadIdx.x;

    // Recompute bucket bases: inclusive scan of bcount over 512 lanes.
    int v = (tid < NB) ? bcount[tid] : 0;
    sb[tid] = v;
    __syncthreads();
    for (int off = 1; off < 512; off <<= 1) {
        int t = (tid >= off) ? sb[tid - off] : 0;
        __syncthreads();
        sb[tid] += t;
        __syncthreads();
    }
    if (tid < NB) {
        sbase[tid] = (sb[tid] - v) + M[blockIdx.x * NB + tid];
        cur[tid] = 0;
    }
    __syncthreads();

    int e0 = blockIdx.x * EPB;
    for (int e = e0 + tid; e < e0 + EPB; e += 512) {
        int d = ei[N_EDGES + e];
        int s = ei[e];
        int b = d >> 8;
        int r = atomicAdd(&cur[b], 1);
        binned[sbase[b] + r] = (s << 8) | (d & 255);   // src:17b | local_dst:8b
    }
}

__global__ __launch_bounds__(512) void bucket_sort(const int* __restrict__ binned,
                                                   const int* __restrict__ bcount,
                                                   int* __restrict__ csr,
                                                   int* __restrict__ offs) {
    __shared__ int sb[512];
    __shared__ int lh[256];
    __shared__ int ls[256];
    __shared__ int lc[256];
    __shared__ int base_sh;
    int tid = threadIdx.x;
    int b = blockIdx.x;

    // Recompute this bucket's base via LDS scan of bcount.
    int v = (tid < NB) ? bcount[tid] : 0;
    sb[tid] = v;
    __syncthreads();
    for (int off = 1; off < 512; off <<= 1) {
        int t = (tid >= off) ? sb[tid - off] : 0;
        __syncthreads();
        sb[tid] += t;
        __syncthreads();
    }
    if (tid == b) base_sh = sb[tid] - v;   // exclusive prefix at b
    __syncthreads();
    int base = base_sh;
    int cnt = bcount[b];

    if (tid < 256) lh[tid] = 0;
    __syncthreads();
    for (int i = tid; i < cnt; i += 512)
        atomicAdd(&lh[binned[base + i] & 255], 1);
    __syncthreads();

    int own = 0;
    if (tid < 256) {
        own = lh[tid];
        ls[tid] = own;
    }
    __syncthreads();
    for (int off = 1; off < 256; off <<= 1) {
        int t = (tid < 256 && tid >= off) ? ls[tid - off] : 0;
        __syncthreads();
        if (tid < 256) ls[tid] += t;
        __syncthreads();
    }

    if (tid < 256) {
        int node = b * SPAN + tid;
        if (node < N_NODES) offs[node] = base + ls[tid];   // end of segment
    }

    int ex = (tid < 256) ? (ls[tid] - own) : 0;
    __syncthreads();
    if (tid < 256) {
        ls[tid] = ex;
        lc[tid] = 0;
    }
    __syncthreads();
    for (int i = tid; i < cnt; i += 512) {
        int en = binned[base + i];
        int ld = en & 255;
        int r = atomicAdd(&lc[ld], 1);
        csr[base + ls[ld] + r] = en >> 8;
    }
}

// ===========================================================================
// x (fp32) -> bf16 copy, with a zero row at index N_NODES (gather pad).
// ===========================================================================
__global__ void to_bf16(const float4* __restrict__ x4,
                        ushort4* __restrict__ xb) {
    int i = blockIdx.x * blockDim.x + threadIdx.x;
    const int n4 = N_NODES * 16;
    if (i < n4) {
        float4 v = x4[i];
        ushort4 o;
        o.x = f2bf(v.x); o.y = f2bf(v.y); o.z = f2bf(v.z); o.w = f2bf(v.w);
        xb[i] = o;
    } else if (i < n4 + 16) {
        xb[i] = make_ushort4(0, 0, 0, 0);   // zero pad row
    }
}

// ===========================================================================
// Fused bf16 gather-sum + MFMA bf16 2-layer MLP.
// ALL gather reads (self + neighbors) hit only the 12.8 MB bf16 copy ->
// small pure footprint maximizes L2 hit rate; fp32 accumulate.
// 512 threads = 8 waves = 32 nodes/block (4 nodes/wave, two dual-node
// passes). Tail slots clamp to the zero pad row (no predication).
// ===========================================================================
__global__ __launch_bounds__(512) void gather_mfma_bf16(
    const uint2* __restrict__ xb2, const int* __restrict__ offs,
    const int* __restrict__ csr, float* __restrict__ out,
    const float* __restrict__ W1, const float* __restrict__ b1,
    const float* __restrict__ W2, const float* __restrict__ b2) {

    __shared__ unsigned short shA[32][72];   // h  (bf16)
    __shared__ unsigned short sh1[32][72];   // relu(h@W1+b1) (bf16)
    __shared__ unsigned short W1t[64][72];   // W1^T [j][k] bf16
    __shared__ unsigned short W2t[64][72];   // W2^T [j][k] bf16

    int tid = threadIdx.x;
    int w = tid >> 6;
    int lane = tid & 63;

    // --- Stage W1^T / W2^T as bf16 (coalesced reads, b128 LDS stores) ---
    {
        int j = lane;               // output feature (row of Wt)
        int kc = w;                 // k-chunk 0..7
        unsigned p1[4], p2[4];
#pragma unroll
        for (int h = 0; h < 4; ++h) {
            float a0 = W1[(kc * 8 + 2 * h) * 64 + j];
            float a1 = W1[(kc * 8 + 2 * h + 1) * 64 + j];
            p1[h] = (unsigned)f2bf(a0) | ((unsigned)f2bf(a1) << 16);
            float c0 = W2[(kc * 8 + 2 * h) * 64 + j];
            float c1 = W2[(kc * 8 + 2 * h + 1) * 64 + j];
            p2[h] = (unsigned)f2bf(c0) | ((unsigned)f2bf(c1) << 16);
        }
        *(uint4*)&W1t[j][kc * 8] = make_uint4(p1[0], p1[1], p1[2], p1[3]);
        *(uint4*)&W2t[j][kc * 8] = make_uint4(p2[0], p2[1], p2[2], p2[3]);
    }

    int s = lane >> 4;               // neighbor slot 0..3
    int c = lane & 15;               // 8B chunk (4 features) of the row
    int nodeBase = blockIdx.x * 32 + 4 * w;

#define ACCQ(acc, q)                                                \
    {                                                               \
        acc.x += __uint_as_float((q).x << 16);                      \
        acc.y += __uint_as_float((q).x & 0xffff0000u);              \
        acc.z += __uint_as_float((q).y << 16);                      \
        acc.w += __uint_as_float((q).y & 0xffff0000u);              \
    }

#pragma unroll
    for (int g = 0; g < 2; ++g) {
        int nA = nodeBase + 2 * g;
        int nB = nA + 1;
        int stA = (nA == 0) ? 0 : offs[nA - 1];
        int enA = offs[nA];
        int stB = offs[nB - 1];
        int enB = offs[nB];

        float4 accA = make_float4(0.f, 0.f, 0.f, 0.f);
        float4 accB = accA;
        if (s == 0) {
            uint2 qa = xb2[(size_t)nA * 16 + c];   // self term (bf16)
            uint2 qb = xb2[(size_t)nB * 16 + c];
            ACCQ(accA, qa);
            ACCQ(accB, qb);
        }

        for (int bA = stA, bB = stB; bA < enA || bB < enB; bA += 16, bB += 16) {
            int pA = bA + s, pB = bB + s;
            if (bA + 16 <= enA && bB + 16 <= enB) {
                int a0 = csr[pA], a1 = csr[pA + 4], a2 = csr[pA + 8], a3 = csr[pA + 12];
                int b0 = csr[pB], b1i = csr[pB + 4], b2i = csr[pB + 8], b3i = csr[pB + 12];
                uint2 qA0 = xb2[(size_t)a0 * 16 + c];
                uint2 qA1 = xb2[(size_t)a1 * 16 + c];
                uint2 qA2 = xb2[(size_t)a2 * 16 + c];
                uint2 qA3 = xb2[(size_t)a3 * 16 + c];
                uint2 qB0 = xb2[(size_t)b0 * 16 + c];
                uint2 qB1 = xb2[(size_t)b1i * 16 + c];
                uint2 qB2 = xb2[(size_t)b2i * 16 + c];
                uint2 qB3 = xb2[(size_t)b3i * 16 + c];
                ACCQ(accA, qA0); ACCQ(accA, qA1); ACCQ(accA, qA2); ACCQ(accA, qA3);
                ACCQ(accB, qB0); ACCQ(accB, qB1); ACCQ(accB, qB2); ACCQ(accB, qB3);
            } else {
                // Tail: clamp out-of-range slots to the zero pad row.
                int a0 = (pA      < enA) ? csr[pA]      : N_NODES;
                int a1 = (pA + 4  < enA) ? csr[pA + 4]  : N_NODES;
                int a2 = (pA + 8  < enA) ? csr[pA + 8]  : N_NODES;
                int a3 = (pA + 12 < enA) ? csr[pA + 12] : N_NODES;
                int b0 = (pB      < enB) ? csr[pB]      : N_NODES;
                int b1i = (pB + 4 < enB) ? csr[pB + 4]  : N_NODES;
                int b2i = (pB + 8 < enB) ? csr[pB + 8]  : N_NODES;
                int b3i = (pB + 12 < enB) ? csr[pB + 12] : N_NODES;
                uint2 qA0 = xb2[(size_t)a0 * 16 + c];
                uint2 qA1 = xb2[(size_t)a1 * 16 + c];
                uint2 qA2 = xb2[(size_t)a2 * 16 + c];
                uint2 qA3 = xb2[(size_t)a3 * 16 + c];
                uint2 qB0 = xb2[(size_t)b0 * 16 + c];
                uint2 qB1 = xb2[(size_t)b1i * 16 + c];
                uint2 qB2 = xb2[(size_t)b2i * 16 + c];
                uint2 qB3 = xb2[(size_t)b3i * 16 + c];
                ACCQ(accA, qA0); ACCQ(accA, qA1); ACCQ(accA, qA2); ACCQ(accA, qA3);
                ACCQ(accB, qB0); ACCQ(accB, qB1); ACCQ(accB, qB2); ACCQ(accB, qB3);
            }
        }

        // Reduce the 4 neighbor slots.
        accA.x += __shfl_xor(accA.x, 16); accA.y += __shfl_xor(accA.y, 16);
        accA.z += __shfl_xor(accA.z, 16); accA.w += __shfl_xor(accA.w, 16);
        accA.x += __shfl_xor(accA.x, 32); accA.y += __shfl_xor(accA.y, 32);
        accA.z += __shfl_xor(accA.z, 32); accA.w += __shfl_xor(accA.w, 32);
        accB.x += __shfl_xor(accB.x, 16); accB.y += __shfl_xor(accB.y, 16);
        accB.z += __shfl_xor(accB.z, 16); accB.w += __shfl_xor(accB.w, 16);
        accB.x += __shfl_xor(accB.x, 32); accB.y += __shfl_xor(accB.y, 32);
        accB.z += __shfl_xor(accB.z, 32); accB.w += __shfl_xor(accB.w, 32);

        if (s == 0) {
            ushort4 ra, rb;
            ra.x = f2bf(accA.x); ra.y = f2bf(accA.y);
            ra.z = f2bf(accA.z); ra.w = f2bf(accA.w);
            rb.x = f2bf(accB.x); rb.y = f2bf(accB.y);
            rb.z = f2bf(accB.z); rb.w = f2bf(accB.w);
            *(ushort4*)&shA[4 * w + 2 * g][c * 4] = ra;
            *(ushort4*)&shA[4 * w + 2 * g + 1][c * 4] = rb;
        }
    }
#undef ACCQ
    __syncthreads();   // shA, W1t, W2t ready

    int row = lane & 15;
    int kg = lane >> 4;
    int rg = w >> 2;                 // row-group 0/1
    int ct = w & 3;                  // col-tile 0..3
    int jj = ct * 16 + row;

    // --- Layer 1 (all 8 waves) ---
    {
        bf16x8 a0 = *(bf16x8*)&shA[rg * 16 + row][kg * 8];
        bf16x8 a1 = *(bf16x8*)&shA[rg * 16 + row][32 + kg * 8];
        bf16x8 w0 = *(bf16x8*)&W1t[jj][kg * 8];
        bf16x8 w1 = *(bf16x8*)&W1t[jj][32 + kg * 8];
        f32x4 d = {0.f, 0.f, 0.f, 0.f};
        d = __builtin_amdgcn_mfma_f32_16x16x32_bf16(a0, w0, d, 0, 0, 0);
        d = __builtin_amdgcn_mfma_f32_16x16x32_bf16(a1, w1, d, 0, 0, 0);
        float bias = b1[jj];
#pragma unroll
        for (int i = 0; i < 4; ++i) {
            float v = fmaxf(d[i] + bias, 0.f);
            sh1[rg * 16 + kg * 4 + i][jj] = f2bf(v);
        }
    }

    bf16x8 w20 = *(bf16x8*)&W2t[jj][kg * 8];
    bf16x8 w21 = *(bf16x8*)&W2t[jj][32 + kg * 8];
    __syncthreads();   // sh1 ready

    // --- Layer 2 (all 8 waves) + store ---
    {
        bf16x8 a0 = *(bf16x8*)&sh1[rg * 16 + row][kg * 8];
        bf16x8 a1 = *(bf16x8*)&sh1[rg * 16 + row][32 + kg * 8];
        f32x4 d = {0.f, 0.f, 0.f, 0.f};
        d = __builtin_amdgcn_mfma_f32_16x16x32_bf16(a0, w20, d, 0, 0, 0);
        d = __builtin_amdgcn_mfma_f32_16x16x32_bf16(a1, w21, d, 0, 0, 0);
        float bias = b2[jj];
        int nbase = blockIdx.x * 32 + rg * 16 + kg * 4;
#pragma unroll
        for (int i = 0; i < 4; ++i)
            out[(size_t)(nbase + i) * 64 + jj] = d[i] + bias;
    }
}

// ===========================================================================
// Round-10 fp32-gather MFMA kernel (fallback if ws too small for xb).
// ===========================================================================
__global__ __launch_bounds__(512) void gather_mfma(
    const float4* __restrict__ x4, const int* __restrict__ offs,
    const int* __restrict__ csr, float* __restrict__ out,
    const float* __restrict__ W1, const float* __restrict__ b1,
    const float* __restrict__ W2, const float* __restrict__ b2) {

    __shared__ unsigned short shA[32][72];
    __shared__ unsigned short sh1[32][72];
    __shared__ unsigned short W1t[64][72];
    __shared__ unsigned short W2t[64][72];

    int tid = threadIdx.x;
    int w = tid >> 6;
    int lane = tid & 63;

    {
        int j = lane;
        int kc = w;
        unsigned p1[4], p2[4];
#pragma unroll
        for (int h = 0; h < 4; ++h) {
            float a0 = W1[(kc * 8 + 2 * h) * 64 + j];
            float a1 = W1[(kc * 8 + 2 * h + 1) * 64 + j];
            p1[h] = (unsigned)f2bf(a0) | ((unsigned)f2bf(a1) << 16);
            float c0 = W2[(kc * 8 + 2 * h) * 64 + j];
            float c1 = W2[(kc * 8 + 2 * h + 1) * 64 + j];
            p2[h] = (unsigned)f2bf(c0) | ((unsigned)f2bf(c1) << 16);
        }
        *(uint4*)&W1t[j][kc * 8] = make_uint4(p1[0], p1[1], p1[2], p1[3]);
        *(uint4*)&W2t[j][kc * 8] = make_uint4(p2[0], p2[1], p2[2], p2[3]);
    }

    int s = lane >> 4;
    int c = lane & 15;
    int nodeBase = blockIdx.x * 32 + 4 * w;

#pragma unroll
    for (int g = 0; g < 2; ++g) {
        int nA = nodeBase + 2 * g;
        int nB = nA + 1;
        int stA = (nA == 0) ? 0 : offs[nA - 1];
        int enA = offs[nA];
        int stB = offs[nB - 1];
        int enB = offs[nB];

        float4 accA = make_float4(0.f, 0.f, 0.f, 0.f);
        float4 accB = accA;
        if (s == 0) {
            accA = x4[(size_t)nA * 16 + c];
            accB = x4[(size_t)nB * 16 + c];
        }

        for (int bA = stA, bB = stB; bA < enA || bB < enB; bA += 16, bB += 16) {
            int pA = bA + s, pB = bB + s;
            int a0 = (pA      < enA) ? csr[pA]      : -1;
            int a1 = (pA + 4  < enA) ? csr[pA + 4]  : -1;
            int a2 = (pA + 8  < enA) ? csr[pA + 8]  : -1;
            int a3 = (pA + 12 < enA) ? csr[pA + 12] : -1;
            int b0 = (pB      < enB) ? csr[pB]      : -1;
            int b1i = (pB + 4 < enB) ? csr[pB + 4]  : -1;
            int b2i = (pB + 8 < enB) ? csr[pB + 8]  : -1;
            int b3i = (pB + 12 < enB) ? csr[pB + 12] : -1;
            float4 vA0 = x4[(size_t)max(a0, 0) * 16 + c];
            float4 vA1 = x4[(size_t)max(a1, 0) * 16 + c];
            float4 vA2 = x4[(size_t)max(a2, 0) * 16 + c];
            float4 vA3 = x4[(size_t)max(a3, 0) * 16 + c];
            float4 vB0 = x4[(size_t)max(b0, 0) * 16 + c];
            float4 vB1 = x4[(size_t)max(b1i, 0) * 16 + c];
            float4 vB2 = x4[(size_t)max(b2i, 0) * 16 + c];
            float4 vB3 = x4[(size_t)max(b3i, 0) * 16 + c];
            if (a0 >= 0) { accA.x += vA0.x; accA.y += vA0.y; accA.z += vA0.z; accA.w += vA0.w; }
            if (a1 >= 0) { accA.x += vA1.x; accA.y += vA1.y; accA.z += vA1.z; accA.w += vA1.w; }
            if (a2 >= 0) { accA.x += vA2.x; accA.y += vA2.y; accA.z += vA2.z; accA.w += vA2.w; }
            if (a3 >= 0) { accA.x += vA3.x; accA.y += vA3.y; accA.z += vA3.z; accA.w += vA3.w; }
            if (b0 >= 0) { accB.x += vB0.x; accB.y += vB0.y; accB.z += vB0.z; accB.w += vB0.w; }
            if (b1i >= 0) { accB.x += vB1.x; accB.y += vB1.y; accB.z += vB1.z; accB.w += vB1.w; }
            if (b2i >= 0) { accB.x += vB2.x; accB.y += vB2.y; accB.z += vB2.z; accB.w += vB2.w; }
            if (b3i >= 0) { accB.x += vB3.x; accB.y += vB3.y; accB.z += vB3.z; accB.w += vB3.w; }
        }

        accA.x += __shfl_xor(accA.x, 16); accA.y += __shfl_xor(accA.y, 16);
        accA.z += __shfl_xor(accA.z, 16); accA.w += __shfl_xor(accA.w, 16);
        accA.x += __shfl_xor(accA.x, 32); accA.y += __shfl_xor(accA.y, 32);
        accA.z += __shfl_xor(accA.z, 32); accA.w += __shfl_xor(accA.w, 32);
        accB.x += __shfl_xor(accB.x, 16); accB.y += __shfl_xor(accB.y, 16);
        accB.z += __shfl_xor(accB.z, 16); accB.w += __shfl_xor(accB.w, 16);
        accB.x += __shfl_xor(accB.x, 32); accB.y += __shfl_xor(accB.y, 32);
        accB.z += __shfl_xor(accB.z, 32); accB.w += __shfl_xor(accB.w, 32);

        if (s == 0) {
            ushort4 ra, rb;
            ra.x = f2bf(accA.x); ra.y = f2bf(accA.y);
            ra.z = f2bf(accA.z); ra.w = f2bf(accA.w);
            rb.x = f2bf(accB.x); rb.y = f2bf(accB.y);
            rb.z = f2bf(accB.z); rb.w = f2bf(accB.w);
            *(ushort4*)&shA[4 * w + 2 * g][c * 4] = ra;
            *(ushort4*)&shA[4 * w + 2 * g + 1][c * 4] = rb;
        }
    }
    __syncthreads();

    int row = lane & 15;
    int kg = lane >> 4;
    int rg = w >> 2;
    int ct = w & 3;
    int jj = ct * 16 + row;

    {
        bf16x8 a0 = *(bf16x8*)&shA[rg * 16 + row][kg * 8];
        bf16x8 a1 = *(bf16x8*)&shA[rg * 16 + row][32 + kg * 8];
        bf16x8 w0 = *(bf16x8*)&W1t[jj][kg * 8];
        bf16x8 w1 = *(bf16x8*)&W1t[jj][32 + kg * 8];
        f32x4 d = {0.f, 0.f, 0.f, 0.f};
        d = __builtin_amdgcn_mfma_f32_16x16x32_bf16(a0, w0, d, 0, 0, 0);
        d = __builtin_amdgcn_mfma_f32_16x16x32_bf16(a1, w1, d, 0, 0, 0);
        float bias = b1[jj];
#pragma unroll
        for (int i = 0; i < 4; ++i) {
            float v = fmaxf(d[i] + bias, 0.f);
            sh1[rg * 16 + kg * 4 + i][jj] = f2bf(v);
        }
    }

    bf16x8 w20 = *(bf16x8*)&W2t[jj][kg * 8];
    bf16x8 w21 = *(bf16x8*)&W2t[jj][32 + kg * 8];
    __syncthreads();

    {
        bf16x8 a0 = *(bf16x8*)&sh1[rg * 16 + row][kg * 8];
        bf16x8 a1 = *(bf16x8*)&sh1[rg * 16 + row][32 + kg * 8];
        f32x4 d = {0.f, 0.f, 0.f, 0.f};
        d = __builtin_amdgcn_mfma_f32_16x16x32_bf16(a0, w20, d, 0, 0, 0);
        d = __builtin_amdgcn_mfma_f32_16x16x32_bf16(a1, w21, d, 0, 0, 0);
        float bias = b2[jj];
        int nbase = blockIdx.x * 32 + rg * 16 + kg * 4;
#pragma unroll
        for (int i = 0; i < 4; ++i)
            out[(size_t)(nbase + i) * 64 + jj] = d[i] + bias;
    }
}

// ===========================================================================
// Round-5 fp32-gather + VALU MLP kernel (mid fallback) — full definition.
// ===========================================================================
__global__ __launch_bounds__(512) void gather_mlp(
    const float4* __restrict__ x4, const int* __restrict__ offs,
    const int* __restrict__ csr, float* __restrict__ out,
    const float* __restrict__ W1, const float* __restrict__ b1,
    const float* __restrict__ W2, const float* __restrict__ b2) {
    __shared__ float sW1[64][64];
    __shared__ float sW2[64][64];
    __shared__ float sb1[64];
    __shared__ float sb2[64];
    __shared__ float sh[8][64];
    __shared__ float sh1[8][64];

    int tid = threadIdx.x;
    for (int i = tid; i < 4096; i += 512) {
        sW1[i >> 6][i & 63] = W1[i];
        sW2[i >> 6][i & 63] = W2[i];
    }
    if (tid < 64) {
        sb1[tid] = b1[tid];
        sb2[tid] = b2[tid];
    }

    int local = tid >> 6;
    int lane = tid & 63;
    int s = lane >> 4;
    int c = lane & 15;
    int node = blockIdx.x * 8 + local;

    int start = (node == 0) ? 0 : offs[node - 1];
    int end = offs[node];

    float4 acc = make_float4(0.f, 0.f, 0.f, 0.f);
    float4 self = x4[(size_t)node * 16 + c];
    if (s == 0) acc = self;

    for (int b = start; b < end; b += 16) {
        int p = b + s;
        int i0 = (p < end) ? csr[p] : -1;
        int i1 = (p + 4 < end) ? csr[p + 4] : -1;
        int i2 = (p + 8 < end) ? csr[p + 8] : -1;
        int i3 = (p + 12 < end) ? csr[p + 12] : -1;
        float4 v0 = x4[(size_t)max(i0, 0) * 16 + c];
        float4 v1 = x4[(size_t)max(i1, 0) * 16 + c];
        float4 v2 = x4[(size_t)max(i2, 0) * 16 + c];
        float4 v3 = x4[(size_t)max(i3, 0) * 16 + c];
        if (i0 >= 0) { acc.x += v0.x; acc.y += v0.y; acc.z += v0.z; acc.w += v0.w; }
        if (i1 >= 0) { acc.x += v1.x; acc.y += v1.y; acc.z += v1.z; acc.w += v1.w; }
        if (i2 >= 0) { acc.x += v2.x; acc.y += v2.y; acc.z += v2.z; acc.w += v2.w; }
        if (i3 >= 0) { acc.x += v3.x; acc.y += v3.y; acc.z += v3.z; acc.w += v3.w; }
    }

    acc.x += __shfl_xor(acc.x, 16); acc.y += __shfl_xor(acc.y, 16);
    acc.z += __shfl_xor(acc.z, 16); acc.w += __shfl_xor(acc.w, 16);
    acc.x += __shfl_xor(acc.x, 32); acc.y += __shfl_xor(acc.y, 32);
    acc.z += __shfl_xor(acc.z, 32); acc.w += __shfl_xor(acc.w, 32);

    __syncthreads();
    if (s == 0) *(float4*)&sh[local][c * 4] = acc;
    __syncthreads();

    int j = lane;
    float a1 = sb1[j];
#pragma unroll
    for (int k = 0; k < 64; ++k) a1 = fmaf(sh[local][k], sW1[k][j], a1);
    a1 = fmaxf(a1, 0.0f);
    sh1[local][j] = a1;
    __syncthreads();

    float a2 = sb2[j];
#pragma unroll
    for (int k = 0; k < 64; ++k) a2 = fmaf(sh1[local][k], sW2[k][j], a2);
    out[(size_t)node * 64 + j] = a2;
}

// ===========================================================================
// Legacy scan build + atomic fallback (unchanged).
// ===========================================================================
__global__ void zero_ints(int* __restrict__ p, int n) {
    int i = blockIdx.x * blockDim.x + threadIdx.x;
    if (i < n) p[i] = 0;
}

__global__ void count_deg(const int* __restrict__ ei, int* __restrict__ deg) {
    int e = blockIdx.x * blockDim.x + threadIdx.x;
    if (e < N_EDGES) atomicAdd(&deg[ei[N_EDGES + e]], 1);
}

__global__ __launch_bounds__(256) void scan_a(const int* __restrict__ deg,
                                              int* __restrict__ offs,
                                              int* __restrict__ bsum) {
    __shared__ int lds[256];
    int tid = threadIdx.x;
    int base = blockIdx.x * SCAN_CHUNK + tid * 8;
    int v[8], ex[8];
    int run = 0;
#pragma unroll
    for (int k = 0; k < 8; ++k) {
        v[k] = (base + k < N_NODES) ? deg[base + k] : 0;
        ex[k] = run;
        run += v[k];
    }
    lds[tid] = run;
    __syncthreads();
    for (int off = 1; off < 256; off <<= 1) {
        int t = (tid >= off) ? lds[tid - off] : 0;
        __syncthreads();
        lds[tid] += t;
        __syncthreads();
    }
    int prefix = lds[tid] - run;
#pragma unroll
    for (int k = 0; k < 8; ++k)
        if (base + k < N_NODES) offs[base + k] = prefix + ex[k];
    if (tid == 0) bsum[blockIdx.x] = lds[255];
}

__global__ void scan_c(int* __restrict__ offs, const int* __restrict__ bsum) {
    int i = blockIdx.x * blockDim.x + threadIdx.x;
    if (i >= N_NODES) return;
    int chunk = i / SCAN_CHUNK;
    int add = 0;
    for (int t = 0; t < chunk; ++t) add += bsum[t];
    offs[i] += add;
}

__global__ void fill_csr(const int* __restrict__ ei, int* __restrict__ offs,
                         int* __restrict__ csr) {
    int e = blockIdx.x * blockDim.x + threadIdx.x;
    if (e >= N_EDGES) return;
    int src = ei[e];
    int dst = ei[N_EDGES + e];
    int pos = atomicAdd(&offs[dst], 1);
    csr[pos] = src;
}

__global__ void init_h(const float4* __restrict__ x, float4* __restrict__ h,
                       int n4) {
    int i = blockIdx.x * blockDim.x + threadIdx.x;
    if (i < n4) h[i] = x[i];
}

__global__ void scatter_add(const float4* __restrict__ x4,
                            const int* __restrict__ ei,
                            float* __restrict__ h) {
    long long i = (long long)blockIdx.x * blockDim.x + threadIdx.x;
    if (i >= (long long)N_EDGES * 16) return;
    int e = (int)(i >> 4);
    int lane = (int)(i & 15);
    int src = ei[e];
    int dst = ei[N_EDGES + e];
    float4 v = x4[(long long)src * 16 + lane];
    float* p = h + (long long)dst * 64 + lane * 4;
    unsafeAtomicAdd(p + 0, v.x);
    unsafeAtomicAdd(p + 1, v.y);
    unsafeAtomicAdd(p + 2, v.z);
    unsafeAtomicAdd(p + 3, v.w);
}

__global__ __launch_bounds__(256) void mlp(float* __restrict__ h,
                                           const float* __restrict__ W1,
                                           const float* __restrict__ b1,
                                           const float* __restrict__ W2,
                                           const float* __restrict__ b2) {
    __shared__ float sW1[64][64];
    __shared__ float sW2[64][64];
    __shared__ float sb1[64];
    __shared__ float sb2[64];
    __shared__ float sh[4][64];
    __shared__ float sh1[4][64];
    int tid = threadIdx.x;
    for (int i = tid; i < 4096; i += 256) {
        sW1[i >> 6][i & 63] = W1[i];
        sW2[i >> 6][i & 63] = W2[i];
    }
    if (tid < 64) { sb1[tid] = b1[tid]; sb2[tid] = b2[tid]; }
    __syncthreads();
    int local = tid >> 6, j = tid & 63;
    int node = blockIdx.x * 4 + local;
    sh[local][j] = h[(long long)node * 64 + j];
    __syncthreads();
    float acc = sb1[j];
#pragma unroll
    for (int k = 0; k < 64; ++k) acc = fmaf(sh[local][k], sW1[k][j], acc);
    acc = fmaxf(acc, 0.0f);
    sh1[local][j] = acc;
    __syncthreads();
    float acc2 = sb2[j];
#pragma unroll
    for (int k = 0; k < 64; ++k) acc2 = fmaf(sh1[local][k], sW2[k][j], acc2);
    h[(long long)node * 64 + j] = acc2;
}

extern "C" void kernel_launch(void* const* d_in, const int* in_sizes, int n_in,
                              void* d_out, int out_size, void* d_ws, size_t ws_size,
                              hipStream_t stream) {
    const float* x = (const float*)d_in[0];
    const int* ei = (const int*)d_in[1];   // harness stores ints as int32
    const float* W1 = (const float*)d_in[2];
    const float* b1 = (const float*)d_in[3];
    const float* W2 = (const float*)d_in[4];
    const float* b2 = (const float*)d_in[5];
    float* out = (float*)d_out;

    size_t need_csr = (size_t)(N_NODES + NBLK_A * NB + NB +
                               2 * N_EDGES) * sizeof(int);
    size_t xb_off = (need_csr + 15) & ~(size_t)15;
    size_t need_bf16 = xb_off + (size_t)(N_NODES + 1) * 64 * 2;
    size_t need_mid = (size_t)(2 * N_NODES + SCAN_BLOCKS + N_EDGES) * sizeof(int);

    if (ws_size >= need_csr) {
        int* offs = (int*)d_ws;
        int* M = offs + N_NODES;
        int* bcount = M + NBLK_A * NB;
        int* binned = bcount + NB;
        int* csr = binned + N_EDGES;

        bool use_bf16 = (ws_size >= need_bf16);
        ushort4* xb = (ushort4*)((char*)d_ws + xb_off);

        if (use_bf16) {
            int nconv = (N_NODES + 1) * 16;
            to_bf16<<<(nconv + 255) / 256, 256, 0, stream>>>((const float4*)x, xb);
        }
        count_buckets<<<NBLK_A, 512, 0, stream>>>(ei, M);
        col_scan<<<NB, 256, 0, stream>>>(M, bcount);
        bin_edges<<<NBLK_A, 512, 0, stream>>>(ei, M, bcount, binned);
        bucket_sort<<<NB, 512, 0, stream>>>(binned, bcount, csr, offs);
        if (use_bf16) {
            gather_mfma_bf16<<<N_NODES / 32, 512, 0, stream>>>(
                (const uint2*)xb, offs, csr, out, W1, b1, W2, b2);
        } else {
            gather_mfma<<<N_NODES / 32, 512, 0, stream>>>(
                (const float4*)x, offs, csr, out, W1, b1, W2, b2);
        }
    } else if (ws_size >= need_mid) {
        int* deg = (int*)d_ws;
        int* offs = deg + N_NODES;
        int* bsum = offs + N_NODES;
        int* csr = bsum + SCAN_BLOCKS;

        zero_ints<<<(N_NODES + 255) / 256, 256, 0, stream>>>(deg, N_NODES);
        count_deg<<<(N_EDGES + 255) / 256, 256, 0, stream>>>(ei, deg);
        scan_a<<<SCAN_BLOCKS, 256, 0, stream>>>(deg, offs, bsum);
        scan_c<<<(N_NODES + 255) / 256, 256, 0, stream>>>(offs, bsum);
        fill_csr<<<(N_EDGES + 255) / 256, 256, 0, stream>>>(ei, offs, csr);
        gather_mlp<<<N_NODES / 8, 512, 0, stream>>>((const float4*)x, offs,
                                                    csr, out, W1, b1, W2, b2);
    } else {
        int n4 = N_NODES * 64 / 4;
        init_h<<<(n4 + 255) / 256, 256, 0, stream>>>((const float4*)x,
                                                     (float4*)out, n4);
        long long nwork = (long long)N_EDGES * 16;
        scatter_add<<<(int)((nwork + 255) / 256), 256, 0, stream>>>(
            (const float4*)x, ei, out);
        mlp<<<N_NODES / 4, 256, 0, stream>>>(out, W1, b1, W2, b2);
    }
}

// Round 13
// 104.609 us; speedup vs baseline: 1.0172x; 1.0172x over previous
//
#include <hip/hip_runtime.h>

#define N_NODES 100000
#define N_EDGES 1600000

// --- bucket-sort build parameters ---
#define SPAN 256
#define NB 391                        // ceil(100000/256)
#define NBLK_A 256
#define EPB (N_EDGES / NBLK_A)        // 6250

// --- legacy path parameters ---
#define SCAN_CHUNK 2048
#define SCAN_BLOCKS ((N_NODES + SCAN_CHUNK - 1) / SCAN_CHUNK)

typedef __attribute__((ext_vector_type(8))) short bf16x8;
typedef __attribute__((ext_vector_type(4))) float f32x4;

static __device__ __forceinline__ unsigned short f2bf(float f) {
    unsigned u = __float_as_uint(f);
    unsigned r = (u + 0x7FFF + ((u >> 16) & 1)) >> 16;   // RNE
    return (unsigned short)r;
}

// ===========================================================================
// Build: deterministic two-level bucket sort, no global atomics.
// ws (ints): offs[N] | M[NBLK_A*NB] | bcount[NB] | binned[E] | csr[E] | xb
// count_buckets ALSO converts x -> bf16 xb (fused: hides 38MB of streaming
// under the histogram's LDS-atomic latency; saves a standalone launch that
// cost ~8 us in round 12).
// ===========================================================================

__global__ __launch_bounds__(512) void count_buckets(const int* __restrict__ ei,
                                                     int* __restrict__ M,
                                                     const float4* __restrict__ x4,
                                                     ushort4* __restrict__ xb) {
    __shared__ int hist[NB];
    int tid = threadIdx.x;
    for (int i = tid; i < NB; i += 512) hist[i] = 0;
    __syncthreads();

    // Fused fp32 -> bf16 conversion (grid-stride over (N+1)*16 float4s;
    // row N_NODES is the zero pad row). Independent of the histogram.
    if (xb) {
        const int n4 = N_NODES * 16;
        const int total = n4 + 16;
        int stride = gridDim.x * 512;
        for (int i = blockIdx.x * 512 + tid; i < total; i += stride) {
            if (i < n4) {
                float4 v = x4[i];
                ushort4 o;
                o.x = f2bf(v.x); o.y = f2bf(v.y);
                o.z = f2bf(v.z); o.w = f2bf(v.w);
                xb[i] = o;
            } else {
                xb[i] = make_ushort4(0, 0, 0, 0);
            }
        }
    }

    int e0 = blockIdx.x * EPB;
    for (int e = e0 + tid; e < e0 + EPB; e += 512)
        atomicAdd(&hist[ei[N_EDGES + e] >> 8], 1);
    __syncthreads();
    for (int i = tid; i < NB; i += 512) M[blockIdx.x * NB + i] = hist[i];
}

// One block per bucket: parallel LDS scan over the 256 per-block counts.
__global__ __launch_bounds__(256) void col_scan(int* __restrict__ M,
                                                int* __restrict__ bcount) {
    __shared__ int s[256];
    int b = blockIdx.x;          // bucket
    int t = threadIdx.x;         // source block
    int v = M[t * NB + b];
    s[t] = v;
    __syncthreads();
    for (int off = 1; off < 256; off <<= 1) {
        int u = (t >= off) ? s[t - off] : 0;
        __syncthreads();
        s[t] += u;
        __syncthreads();
    }
    M[t * NB + b] = s[t] - v;    // exclusive offset of block t within bucket b
    if (t == 255) bcount[b] = s[255];
}

__global__ __launch_bounds__(512) void bin_edges(const int* __restrict__ ei,
                                                 const int* __restrict__ M,
                                                 const int* __restrict__ bcount,
                                                 int* __restrict__ binned) {
    __shared__ int sb[512];
    __shared__ int sbase[NB];
    __shared__ int cur[NB];
    int tid = threadIdx.x;

    // Recompute bucket bases: inclusive scan of bcount over 512 lanes.
    int v = (tid < NB) ? bcount[tid] : 0;
    sb[tid] = v;
    __syncthreads();
    for (int off = 1; off < 512; off <<= 1) {
        int t = (tid >= off) ? sb[tid - off] : 0;
        __syncthreads();
        sb[tid] += t;
        __syncthreads();
    }
    if (tid < NB) {
        sbase[tid] = (sb[tid] - v) + M[blockIdx.x * NB + tid];
        cur[tid] = 0;
    }
    __syncthreads();

    int e0 = blockIdx.x * EPB;
    for (int e = e0 + tid; e < e0 + EPB; e += 512) {
        int d = ei[N_EDGES + e];
        int s = ei[e];
        int b = d >> 8;
        int r = atomicAdd(&cur[b], 1);
        binned[sbase[b] + r] = (s << 8) | (d & 255);   // src:17b | local_dst:8b
    }
}

__global__ __launch_bounds__(512) void bucket_sort(const int* __restrict__ binned,
                                                   const int* __restrict__ bcount,
                                                   int* __restrict__ csr,
                                                   int* __restrict__ offs) {
    __shared__ int sb[512];
    __shared__ int lh[256];
    __shared__ int ls[256];
    __shared__ int lc[256];
    __shared__ int base_sh;
    int tid = threadIdx.x;
    int b = blockIdx.x;

    // Recompute this bucket's base via LDS scan of bcount.
    int v = (tid < NB) ? bcount[tid] : 0;
    sb[tid] = v;
    __syncthreads();
    for (int off = 1; off < 512; off <<= 1) {
        int t = (tid >= off) ? sb[tid - off] : 0;
        __syncthreads();
        sb[tid] += t;
        __syncthreads();
    }
    if (tid == b) base_sh = sb[tid] - v;   // exclusive prefix at b
    __syncthreads();
    int base = base_sh;
    int cnt = bcount[b];

    if (tid < 256) lh[tid] = 0;
    __syncthreads();
    for (int i = tid; i < cnt; i += 512)
        atomicAdd(&lh[binned[base + i] & 255], 1);
    __syncthreads();

    int own = 0;
    if (tid < 256) {
        own = lh[tid];
        ls[tid] = own;
    }
    __syncthreads();
    for (int off = 1; off < 256; off <<= 1) {
        int t = (tid < 256 && tid >= off) ? ls[tid - off] : 0;
        __syncthreads();
        if (tid < 256) ls[tid] += t;
        __syncthreads();
    }

    if (tid < 256) {
        int node = b * SPAN + tid;
        if (node < N_NODES) offs[node] = base + ls[tid];   // end of segment
    }

    int ex = (tid < 256) ? (ls[tid] - own) : 0;
    __syncthreads();
    if (tid < 256) {
        ls[tid] = ex;
        lc[tid] = 0;
    }
    __syncthreads();
    for (int i = tid; i < cnt; i += 512) {
        int en = binned[base + i];
        int ld = en & 255;
        int r = atomicAdd(&lc[ld], 1);
        csr[base + ls[ld] + r] = en >> 8;
    }
}

// ===========================================================================
// Fused bf16 gather-sum + MFMA bf16 2-layer MLP (round-12 proven: 60.6 us).
// 512 threads = 8 waves = 32 nodes/block (4 nodes/wave, two dual-node
// passes). Tail slots clamp to the zero pad row (no predication).
// ===========================================================================
__global__ __launch_bounds__(512) void gather_mfma_bf16(
    const uint2* __restrict__ xb2, const int* __restrict__ offs,
    const int* __restrict__ csr, float* __restrict__ out,
    const float* __restrict__ W1, const float* __restrict__ b1,
    const float* __restrict__ W2, const float* __restrict__ b2) {

    __shared__ unsigned short shA[32][72];   // h  (bf16)
    __shared__ unsigned short sh1[32][72];   // relu(h@W1+b1) (bf16)
    __shared__ unsigned short W1t[64][72];   // W1^T [j][k] bf16
    __shared__ unsigned short W2t[64][72];   // W2^T [j][k] bf16

    int tid = threadIdx.x;
    int w = tid >> 6;
    int lane = tid & 63;

    // --- Stage W1^T / W2^T as bf16 (coalesced reads, b128 LDS stores) ---
    {
        int j = lane;               // output feature (row of Wt)
        int kc = w;                 // k-chunk 0..7
        unsigned p1[4], p2[4];
#pragma unroll
        for (int h = 0; h < 4; ++h) {
            float a0 = W1[(kc * 8 + 2 * h) * 64 + j];
            float a1 = W1[(kc * 8 + 2 * h + 1) * 64 + j];
            p1[h] = (unsigned)f2bf(a0) | ((unsigned)f2bf(a1) << 16);
            float c0 = W2[(kc * 8 + 2 * h) * 64 + j];
            float c1 = W2[(kc * 8 + 2 * h + 1) * 64 + j];
            p2[h] = (unsigned)f2bf(c0) | ((unsigned)f2bf(c1) << 16);
        }
        *(uint4*)&W1t[j][kc * 8] = make_uint4(p1[0], p1[1], p1[2], p1[3]);
        *(uint4*)&W2t[j][kc * 8] = make_uint4(p2[0], p2[1], p2[2], p2[3]);
    }

    int s = lane >> 4;               // neighbor slot 0..3
    int c = lane & 15;               // 8B chunk (4 features) of the row
    int nodeBase = blockIdx.x * 32 + 4 * w;

#define ACCQ(acc, q)                                                \
    {                                                               \
        acc.x += __uint_as_float((q).x << 16);                      \
        acc.y += __uint_as_float((q).x & 0xffff0000u);              \
        acc.z += __uint_as_float((q).y << 16);                      \
        acc.w += __uint_as_float((q).y & 0xffff0000u);              \
    }

#pragma unroll
    for (int g = 0; g < 2; ++g) {
        int nA = nodeBase + 2 * g;
        int nB = nA + 1;
        int stA = (nA == 0) ? 0 : offs[nA - 1];
        int enA = offs[nA];
        int stB = offs[nB - 1];
        int enB = offs[nB];

        float4 accA = make_float4(0.f, 0.f, 0.f, 0.f);
        float4 accB = accA;
        if (s == 0) {
            uint2 qa = xb2[(size_t)nA * 16 + c];   // self term (bf16)
            uint2 qb = xb2[(size_t)nB * 16 + c];
            ACCQ(accA, qa);
            ACCQ(accB, qb);
        }

        for (int bA = stA, bB = stB; bA < enA || bB < enB; bA += 16, bB += 16) {
            int pA = bA + s, pB = bB + s;
            if (bA + 16 <= enA && bB + 16 <= enB) {
                int a0 = csr[pA], a1 = csr[pA + 4], a2 = csr[pA + 8], a3 = csr[pA + 12];
                int b0 = csr[pB], b1i = csr[pB + 4], b2i = csr[pB + 8], b3i = csr[pB + 12];
                uint2 qA0 = xb2[(size_t)a0 * 16 + c];
                uint2 qA1 = xb2[(size_t)a1 * 16 + c];
                uint2 qA2 = xb2[(size_t)a2 * 16 + c];
                uint2 qA3 = xb2[(size_t)a3 * 16 + c];
                uint2 qB0 = xb2[(size_t)b0 * 16 + c];
                uint2 qB1 = xb2[(size_t)b1i * 16 + c];
                uint2 qB2 = xb2[(size_t)b2i * 16 + c];
                uint2 qB3 = xb2[(size_t)b3i * 16 + c];
                ACCQ(accA, qA0); ACCQ(accA, qA1); ACCQ(accA, qA2); ACCQ(accA, qA3);
                ACCQ(accB, qB0); ACCQ(accB, qB1); ACCQ(accB, qB2); ACCQ(accB, qB3);
            } else {
                // Tail: clamp out-of-range slots to the zero pad row.
                int a0 = (pA      < enA) ? csr[pA]      : N_NODES;
                int a1 = (pA + 4  < enA) ? csr[pA + 4]  : N_NODES;
                int a2 = (pA + 8  < enA) ? csr[pA + 8]  : N_NODES;
                int a3 = (pA + 12 < enA) ? csr[pA + 12] : N_NODES;
                int b0 = (pB      < enB) ? csr[pB]      : N_NODES;
                int b1i = (pB + 4 < enB) ? csr[pB + 4]  : N_NODES;
                int b2i = (pB + 8 < enB) ? csr[pB + 8]  : N_NODES;
                int b3i = (pB + 12 < enB) ? csr[pB + 12] : N_NODES;
                uint2 qA0 = xb2[(size_t)a0 * 16 + c];
                uint2 qA1 = xb2[(size_t)a1 * 16 + c];
                uint2 qA2 = xb2[(size_t)a2 * 16 + c];
                uint2 qA3 = xb2[(size_t)a3 * 16 + c];
                uint2 qB0 = xb2[(size_t)b0 * 16 + c];
                uint2 qB1 = xb2[(size_t)b1i * 16 + c];
                uint2 qB2 = xb2[(size_t)b2i * 16 + c];
                uint2 qB3 = xb2[(size_t)b3i * 16 + c];
                ACCQ(accA, qA0); ACCQ(accA, qA1); ACCQ(accA, qA2); ACCQ(accA, qA3);
                ACCQ(accB, qB0); ACCQ(accB, qB1); ACCQ(accB, qB2); ACCQ(accB, qB3);
            }
        }

        // Reduce the 4 neighbor slots.
        accA.x += __shfl_xor(accA.x, 16); accA.y += __shfl_xor(accA.y, 16);
        accA.z += __shfl_xor(accA.z, 16); accA.w += __shfl_xor(accA.w, 16);
        accA.x += __shfl_xor(accA.x, 32); accA.y += __shfl_xor(accA.y, 32);
        accA.z += __shfl_xor(accA.z, 32); accA.w += __shfl_xor(accA.w, 32);
        accB.x += __shfl_xor(accB.x, 16); accB.y += __shfl_xor(accB.y, 16);
        accB.z += __shfl_xor(accB.z, 16); accB.w += __shfl_xor(accB.w, 16);
        accB.x += __shfl_xor(accB.x, 32); accB.y += __shfl_xor(accB.y, 32);
        accB.z += __shfl_xor(accB.z, 32); accB.w += __shfl_xor(accB.w, 32);

        if (s == 0) {
            ushort4 ra, rb;
            ra.x = f2bf(accA.x); ra.y = f2bf(accA.y);
            ra.z = f2bf(accA.z); ra.w = f2bf(accA.w);
            rb.x = f2bf(accB.x); rb.y = f2bf(accB.y);
            rb.z = f2bf(accB.z); rb.w = f2bf(accB.w);
            *(ushort4*)&shA[4 * w + 2 * g][c * 4] = ra;
            *(ushort4*)&shA[4 * w + 2 * g + 1][c * 4] = rb;
        }
    }
#undef ACCQ
    __syncthreads();   // shA, W1t, W2t ready

    int row = lane & 15;
    int kg = lane >> 4;
    int rg = w >> 2;                 // row-group 0/1
    int ct = w & 3;                  // col-tile 0..3
    int jj = ct * 16 + row;

    // --- Layer 1 (all 8 waves) ---
    {
        bf16x8 a0 = *(bf16x8*)&shA[rg * 16 + row][kg * 8];
        bf16x8 a1 = *(bf16x8*)&shA[rg * 16 + row][32 + kg * 8];
        bf16x8 w0 = *(bf16x8*)&W1t[jj][kg * 8];
        bf16x8 w1 = *(bf16x8*)&W1t[jj][32 + kg * 8];
        f32x4 d = {0.f, 0.f, 0.f, 0.f};
        d = __builtin_amdgcn_mfma_f32_16x16x32_bf16(a0, w0, d, 0, 0, 0);
        d = __builtin_amdgcn_mfma_f32_16x16x32_bf16(a1, w1, d, 0, 0, 0);
        float bias = b1[jj];
#pragma unroll
        for (int i = 0; i < 4; ++i) {
            float v = fmaxf(d[i] + bias, 0.f);
            sh1[rg * 16 + kg * 4 + i][jj] = f2bf(v);
        }
    }

    bf16x8 w20 = *(bf16x8*)&W2t[jj][kg * 8];
    bf16x8 w21 = *(bf16x8*)&W2t[jj][32 + kg * 8];
    __syncthreads();   // sh1 ready

    // --- Layer 2 (all 8 waves) + store ---
    {
        bf16x8 a0 = *(bf16x8*)&sh1[rg * 16 + row][kg * 8];
        bf16x8 a1 = *(bf16x8*)&sh1[rg * 16 + row][32 + kg * 8];
        f32x4 d = {0.f, 0.f, 0.f, 0.f};
        d = __builtin_amdgcn_mfma_f32_16x16x32_bf16(a0, w20, d, 0, 0, 0);
        d = __builtin_amdgcn_mfma_f32_16x16x32_bf16(a1, w21, d, 0, 0, 0);
        float bias = b2[jj];
        int nbase = blockIdx.x * 32 + rg * 16 + kg * 4;
#pragma unroll
        for (int i = 0; i < 4; ++i)
            out[(size_t)(nbase + i) * 64 + jj] = d[i] + bias;
    }
}

// ===========================================================================
// fp32-gather MFMA kernel (fallback if ws too small for xb).
// ===========================================================================
__global__ __launch_bounds__(512) void gather_mfma(
    const float4* __restrict__ x4, const int* __restrict__ offs,
    const int* __restrict__ csr, float* __restrict__ out,
    const float* __restrict__ W1, const float* __restrict__ b1,
    const float* __restrict__ W2, const float* __restrict__ b2) {

    __shared__ unsigned short shA[32][72];
    __shared__ unsigned short sh1[32][72];
    __shared__ unsigned short W1t[64][72];
    __shared__ unsigned short W2t[64][72];

    int tid = threadIdx.x;
    int w = tid >> 6;
    int lane = tid & 63;

    {
        int j = lane;
        int kc = w;
        unsigned p1[4], p2[4];
#pragma unroll
        for (int h = 0; h < 4; ++h) {
            float a0 = W1[(kc * 8 + 2 * h) * 64 + j];
            float a1 = W1[(kc * 8 + 2 * h + 1) * 64 + j];
            p1[h] = (unsigned)f2bf(a0) | ((unsigned)f2bf(a1) << 16);
            float c0 = W2[(kc * 8 + 2 * h) * 64 + j];
            float c1 = W2[(kc * 8 + 2 * h + 1) * 64 + j];
            p2[h] = (unsigned)f2bf(c0) | ((unsigned)f2bf(c1) << 16);
        }
        *(uint4*)&W1t[j][kc * 8] = make_uint4(p1[0], p1[1], p1[2], p1[3]);
        *(uint4*)&W2t[j][kc * 8] = make_uint4(p2[0], p2[1], p2[2], p2[3]);
    }

    int s = lane >> 4;
    int c = lane & 15;
    int nodeBase = blockIdx.x * 32 + 4 * w;

#pragma unroll
    for (int g = 0; g < 2; ++g) {
        int nA = nodeBase + 2 * g;
        int nB = nA + 1;
        int stA = (nA == 0) ? 0 : offs[nA - 1];
        int enA = offs[nA];
        int stB = offs[nB - 1];
        int enB = offs[nB];

        float4 accA = make_float4(0.f, 0.f, 0.f, 0.f);
        float4 accB = accA;
        if (s == 0) {
            accA = x4[(size_t)nA * 16 + c];
            accB = x4[(size_t)nB * 16 + c];
        }

        for (int bA = stA, bB = stB; bA < enA || bB < enB; bA += 16, bB += 16) {
            int pA = bA + s, pB = bB + s;
            int a0 = (pA      < enA) ? csr[pA]      : -1;
            int a1 = (pA + 4  < enA) ? csr[pA + 4]  : -1;
            int a2 = (pA + 8  < enA) ? csr[pA + 8]  : -1;
            int a3 = (pA + 12 < enA) ? csr[pA + 12] : -1;
            int b0 = (pB      < enB) ? csr[pB]      : -1;
            int b1i = (pB + 4 < enB) ? csr[pB + 4]  : -1;
            int b2i = (pB + 8 < enB) ? csr[pB + 8]  : -1;
            int b3i = (pB + 12 < enB) ? csr[pB + 12] : -1;
            float4 vA0 = x4[(size_t)max(a0, 0) * 16 + c];
            float4 vA1 = x4[(size_t)max(a1, 0) * 16 + c];
            float4 vA2 = x4[(size_t)max(a2, 0) * 16 + c];
            float4 vA3 = x4[(size_t)max(a3, 0) * 16 + c];
            float4 vB0 = x4[(size_t)max(b0, 0) * 16 + c];
            float4 vB1 = x4[(size_t)max(b1i, 0) * 16 + c];
            float4 vB2 = x4[(size_t)max(b2i, 0) * 16 + c];
            float4 vB3 = x4[(size_t)max(b3i, 0) * 16 + c];
            if (a0 >= 0) { accA.x += vA0.x; accA.y += vA0.y; accA.z += vA0.z; accA.w += vA0.w; }
            if (a1 >= 0) { accA.x += vA1.x; accA.y += vA1.y; accA.z += vA1.z; accA.w += vA1.w; }
            if (a2 >= 0) { accA.x += vA2.x; accA.y += vA2.y; accA.z += vA2.z; accA.w += vA2.w; }
            if (a3 >= 0) { accA.x += vA3.x; accA.y += vA3.y; accA.z += vA3.z; accA.w += vA3.w; }
            if (b0 >= 0) { accB.x += vB0.x; accB.y += vB0.y; accB.z += vB0.z; accB.w += vB0.w; }
            if (b1i >= 0) { accB.x += vB1.x; accB.y += vB1.y; accB.z += vB1.z; accB.w += vB1.w; }
            if (b2i >= 0) { accB.x += vB2.x; accB.y += vB2.y; accB.z += vB2.z; accB.w += vB2.w; }
            if (b3i >= 0) { accB.x += vB3.x; accB.y += vB3.y; accB.z += vB3.z; accB.w += vB3.w; }
        }

        accA.x += __shfl_xor(accA.x, 16); accA.y += __shfl_xor(accA.y, 16);
        accA.z += __shfl_xor(accA.z, 16); accA.w += __shfl_xor(accA.w, 16);
        accA.x += __shfl_xor(accA.x, 32); accA.y += __shfl_xor(accA.y, 32);
        accA.z += __shfl_xor(accA.z, 32); accA.w += __shfl_xor(accA.w, 32);
        accB.x += __shfl_xor(accB.x, 16); accB.y += __shfl_xor(accB.y, 16);
        accB.z += __shfl_xor(accB.z, 16); accB.w += __shfl_xor(accB.w, 16);
        accB.x += __shfl_xor(accB.x, 32); accB.y += __shfl_xor(accB.y, 32);
        accB.z += __shfl_xor(accB.z, 32); accB.w += __shfl_xor(accB.w, 32);

        if (s == 0) {
            ushort4 ra, rb;
            ra.x = f2bf(accA.x); ra.y = f2bf(accA.y);
            ra.z = f2bf(accA.z); ra.w = f2bf(accA.w);
            rb.x = f2bf(accB.x); rb.y = f2bf(accB.y);
            rb.z = f2bf(accB.z); rb.w = f2bf(accB.w);
            *(ushort4*)&shA[4 * w + 2 * g][c * 4] = ra;
            *(ushort4*)&shA[4 * w + 2 * g + 1][c * 4] = rb;
        }
    }
    __syncthreads();

    int row = lane & 15;
    int kg = lane >> 4;
    int rg = w >> 2;
    int ct = w & 3;
    int jj = ct * 16 + row;

    {
        bf16x8 a0 = *(bf16x8*)&shA[rg * 16 + row][kg * 8];
        bf16x8 a1 = *(bf16x8*)&shA[rg * 16 + row][32 + kg * 8];
        bf16x8 w0 = *(bf16x8*)&W1t[jj][kg * 8];
        bf16x8 w1 = *(bf16x8*)&W1t[jj][32 + kg * 8];
        f32x4 d = {0.f, 0.f, 0.f, 0.f};
        d = __builtin_amdgcn_mfma_f32_16x16x32_bf16(a0, w0, d, 0, 0, 0);
        d = __builtin_amdgcn_mfma_f32_16x16x32_bf16(a1, w1, d, 0, 0, 0);
        float bias = b1[jj];
#pragma unroll
        for (int i = 0; i < 4; ++i) {
            float v = fmaxf(d[i] + bias, 0.f);
            sh1[rg * 16 + kg * 4 + i][jj] = f2bf(v);
        }
    }

    bf16x8 w20 = *(bf16x8*)&W2t[jj][kg * 8];
    bf16x8 w21 = *(bf16x8*)&W2t[jj][32 + kg * 8];
    __syncthreads();

    {
        bf16x8 a0 = *(bf16x8*)&sh1[rg * 16 + row][kg * 8];
        bf16x8 a1 = *(bf16x8*)&sh1[rg * 16 + row][32 + kg * 8];
        f32x4 d = {0.f, 0.f, 0.f, 0.f};
        d = __builtin_amdgcn_mfma_f32_16x16x32_bf16(a0, w20, d, 0, 0, 0);
        d = __builtin_amdgcn_mfma_f32_16x16x32_bf16(a1, w21, d, 0, 0, 0);
        float bias = b2[jj];
        int nbase = blockIdx.x * 32 + rg * 16 + kg * 4;
#pragma unroll
        for (int i = 0; i < 4; ++i)
            out[(size_t)(nbase + i) * 64 + jj] = d[i] + bias;
    }
}

// ===========================================================================
// Round-5 fp32-gather + VALU MLP kernel (mid fallback).
// ===========================================================================
__global__ __launch_bounds__(512) void gather_mlp(
    const float4* __restrict__ x4, const int* __restrict__ offs,
    const int* __restrict__ csr, float* __restrict__ out,
    const float* __restrict__ W1, const float* __restrict__ b1,
    const float* __restrict__ W2, const float* __restrict__ b2) {
    __shared__ float sW1[64][64];
    __shared__ float sW2[64][64];
    __shared__ float sb1[64];
    __shared__ float sb2[64];
    __shared__ float sh[8][64];
    __shared__ float sh1[8][64];

    int tid = threadIdx.x;
    for (int i = tid; i < 4096; i += 512) {
        sW1[i >> 6][i & 63] = W1[i];
        sW2[i >> 6][i & 63] = W2[i];
    }
    if (tid < 64) {
        sb1[tid] = b1[tid];
        sb2[tid] = b2[tid];
    }

    int local = tid >> 6;
    int lane = tid & 63;
    int s = lane >> 4;
    int c = lane & 15;
    int node = blockIdx.x * 8 + local;

    int start = (node == 0) ? 0 : offs[node - 1];
    int end = offs[node];

    float4 acc = make_float4(0.f, 0.f, 0.f, 0.f);
    float4 self = x4[(size_t)node * 16 + c];
    if (s == 0) acc = self;

    for (int b = start; b < end; b += 16) {
        int p = b + s;
        int i0 = (p < end) ? csr[p] : -1;
        int i1 = (p + 4 < end) ? csr[p + 4] : -1;
        int i2 = (p + 8 < end) ? csr[p + 8] : -1;
        int i3 = (p + 12 < end) ? csr[p + 12] : -1;
        float4 v0 = x4[(size_t)max(i0, 0) * 16 + c];
        float4 v1 = x4[(size_t)max(i1, 0) * 16 + c];
        float4 v2 = x4[(size_t)max(i2, 0) * 16 + c];
        float4 v3 = x4[(size_t)max(i3, 0) * 16 + c];
        if (i0 >= 0) { acc.x += v0.x; acc.y += v0.y; acc.z += v0.z; acc.w += v0.w; }
        if (i1 >= 0) { acc.x += v1.x; acc.y += v1.y; acc.z += v1.z; acc.w += v1.w; }
        if (i2 >= 0) { acc.x += v2.x; acc.y += v2.y; acc.z += v2.z; acc.w += v2.w; }
        if (i3 >= 0) { acc.x += v3.x; acc.y += v3.y; acc.z += v3.z; acc.w += v3.w; }
    }

    acc.x += __shfl_xor(acc.x, 16); acc.y += __shfl_xor(acc.y, 16);
    acc.z += __shfl_xor(acc.z, 16); acc.w += __shfl_xor(acc.w, 16);
    acc.x += __shfl_xor(acc.x, 32); acc.y += __shfl_xor(acc.y, 32);
    acc.z += __shfl_xor(acc.z, 32); acc.w += __shfl_xor(acc.w, 32);

    __syncthreads();
    if (s == 0) *(float4*)&sh[local][c * 4] = acc;
    __syncthreads();

    int j = lane;
    float a1 = sb1[j];
#pragma unroll
    for (int k = 0; k < 64; ++k) a1 = fmaf(sh[local][k], sW1[k][j], a1);
    a1 = fmaxf(a1, 0.0f);
    sh1[local][j] = a1;
    __syncthreads();

    float a2 = sb2[j];
#pragma unroll
    for (int k = 0; k < 64; ++k) a2 = fmaf(sh1[local][k], sW2[k][j], a2);
    out[(size_t)node * 64 + j] = a2;
}

// ===========================================================================
// Legacy scan build + atomic fallback (unchanged).
// ===========================================================================
__global__ void zero_ints(int* __restrict__ p, int n) {
    int i = blockIdx.x * blockDim.x + threadIdx.x;
    if (i < n) p[i] = 0;
}

__global__ void count_deg(const int* __restrict__ ei, int* __restrict__ deg) {
    int e = blockIdx.x * blockDim.x + threadIdx.x;
    if (e < N_EDGES) atomicAdd(&deg[ei[N_EDGES + e]], 1);
}

__global__ __launch_bounds__(256) void scan_a(const int* __restrict__ deg,
                                              int* __restrict__ offs,
                                              int* __restrict__ bsum) {
    __shared__ int lds[256];
    int tid = threadIdx.x;
    int base = blockIdx.x * SCAN_CHUNK + tid * 8;
    int v[8], ex[8];
    int run = 0;
#pragma unroll
    for (int k = 0; k < 8; ++k) {
        v[k] = (base + k < N_NODES) ? deg[base + k] : 0;
        ex[k] = run;
        run += v[k];
    }
    lds[tid] = run;
    __syncthreads();
    for (int off = 1; off < 256; off <<= 1) {
        int t = (tid >= off) ? lds[tid - off] : 0;
        __syncthreads();
        lds[tid] += t;
        __syncthreads();
    }
    int prefix = lds[tid] - run;
#pragma unroll
    for (int k = 0; k < 8; ++k)
        if (base + k < N_NODES) offs[base + k] = prefix + ex[k];
    if (tid == 0) bsum[blockIdx.x] = lds[255];
}

__global__ void scan_c(int* __restrict__ offs, const int* __restrict__ bsum) {
    int i = blockIdx.x * blockDim.x + threadIdx.x;
    if (i >= N_NODES) return;
    int chunk = i / SCAN_CHUNK;
    int add = 0;
    for (int t = 0; t < chunk; ++t) add += bsum[t];
    offs[i] += add;
}

__global__ void fill_csr(const int* __restrict__ ei, int* __restrict__ offs,
                         int* __restrict__ csr) {
    int e = blockIdx.x * blockDim.x + threadIdx.x;
    if (e >= N_EDGES) return;
    int src = ei[e];
    int dst = ei[N_EDGES + e];
    int pos = atomicAdd(&offs[dst], 1);
    csr[pos] = src;
}

__global__ void init_h(const float4* __restrict__ x, float4* __restrict__ h,
                       int n4) {
    int i = blockIdx.x * blockDim.x + threadIdx.x;
    if (i < n4) h[i] = x[i];
}

__global__ void scatter_add(const float4* __restrict__ x4,
                            const int* __restrict__ ei,
                            float* __restrict__ h) {
    long long i = (long long)blockIdx.x * blockDim.x + threadIdx.x;
    if (i >= (long long)N_EDGES * 16) return;
    int e = (int)(i >> 4);
    int lane = (int)(i & 15);
    int src = ei[e];
    int dst = ei[N_EDGES + e];
    float4 v = x4[(long long)src * 16 + lane];
    float* p = h + (long long)dst * 64 + lane * 4;
    unsafeAtomicAdd(p + 0, v.x);
    unsafeAtomicAdd(p + 1, v.y);
    unsafeAtomicAdd(p + 2, v.z);
    unsafeAtomicAdd(p + 3, v.w);
}

__global__ __launch_bounds__(256) void mlp(float* __restrict__ h,
                                           const float* __restrict__ W1,
                                           const float* __restrict__ b1,
                                           const float* __restrict__ W2,
                                           const float* __restrict__ b2) {
    __shared__ float sW1[64][64];
    __shared__ float sW2[64][64];
    __shared__ float sb1[64];
    __shared__ float sb2[64];
    __shared__ float sh[4][64];
    __shared__ float sh1[4][64];
    int tid = threadIdx.x;
    for (int i = tid; i < 4096; i += 256) {
        sW1[i >> 6][i & 63] = W1[i];
        sW2[i >> 6][i & 63] = W2[i];
    }
    if (tid < 64) { sb1[tid] = b1[tid]; sb2[tid] = b2[tid]; }
    __syncthreads();
    int local = tid >> 6, j = tid & 63;
    int node = blockIdx.x * 4 + local;
    sh[local][j] = h[(long long)node * 64 + j];
    __syncthreads();
    float acc = sb1[j];
#pragma unroll
    for (int k = 0; k < 64; ++k) acc = fmaf(sh[local][k], sW1[k][j], acc);
    acc = fmaxf(acc, 0.0f);
    sh1[local][j] = acc;
    __syncthreads();
    float acc2 = sb2[j];
#pragma unroll
    for (int k = 0; k < 64; ++k) acc2 = fmaf(sh1[local][k], sW2[k][j], acc2);
    h[(long long)node * 64 + j] = acc2;
}

extern "C" void kernel_launch(void* const* d_in, const int* in_sizes, int n_in,
                              void* d_out, int out_size, void* d_ws, size_t ws_size,
                              hipStream_t stream) {
    const float* x = (const float*)d_in[0];
    const int* ei = (const int*)d_in[1];   // harness stores ints as int32
    const float* W1 = (const float*)d_in[2];
    const float* b1 = (const float*)d_in[3];
    const float* W2 = (const float*)d_in[4];
    const float* b2 = (const float*)d_in[5];
    float* out = (float*)d_out;

    size_t need_csr = (size_t)(N_NODES + NBLK_A * NB + NB +
                               2 * N_EDGES) * sizeof(int);
    size_t xb_off = (need_csr + 15) & ~(size_t)15;
    size_t need_bf16 = xb_off + (size_t)(N_NODES + 1) * 64 * 2;
    size_t need_mid = (size_t)(2 * N_NODES + SCAN_BLOCKS + N_EDGES) * sizeof(int);

    if (ws_size >= need_csr) {
        int* offs = (int*)d_ws;
        int* M = offs + N_NODES;
        int* bcount = M + NBLK_A * NB;
        int* binned = bcount + NB;
        int* csr = binned + N_EDGES;

        bool use_bf16 = (ws_size >= need_bf16);
        ushort4* xb = use_bf16 ? (ushort4*)((char*)d_ws + xb_off) : nullptr;

        count_buckets<<<NBLK_A, 512, 0, stream>>>(ei, M, (const float4*)x, xb);
        col_scan<<<NB, 256, 0, stream>>>(M, bcount);
        bin_edges<<<NBLK_A, 512, 0, stream>>>(ei, M, bcount, binned);
        bucket_sort<<<NB, 512, 0, stream>>>(binned, bcount, csr, offs);
        if (use_bf16) {
            gather_mfma_bf16<<<N_NODES / 32, 512, 0, stream>>>(
                (const uint2*)xb, offs, csr, out, W1, b1, W2, b2);
        } else {
            gather_mfma<<<N_NODES / 32, 512, 0, stream>>>(
                (const float4*)x, offs, csr, out, W1, b1, W2, b2);
        }
    } else if (ws_size >= need_mid) {
        int* deg = (int*)d_ws;
        int* offs = deg + N_NODES;
        int* bsum = offs + N_NODES;
        int* csr = bsum + SCAN_BLOCKS;

        zero_ints<<<(N_NODES + 255) / 256, 256, 0, stream>>>(deg, N_NODES);
        count_deg<<<(N_EDGES + 255) / 256, 256, 0, stream>>>(ei, deg);
        scan_a<<<SCAN_BLOCKS, 256, 0, stream>>>(deg, offs, bsum);
        scan_c<<<(N_NODES + 255) / 256, 256, 0, stream>>>(offs, bsum);
        fill_csr<<<(N_EDGES + 255) / 256, 256, 0, stream>>>(ei, offs, csr);
        gather_mlp<<<N_NODES / 8, 512, 0, stream>>>((const float4*)x, offs,
                                                    csr, out, W1, b1, W2, b2);
    } else {
        int n4 = N_NODES * 64 / 4;
        init_h<<<(n4 + 255) / 256, 256, 0, stream>>>((const float4*)x,
                                                     (float4*)out, n4);
        long long nwork = (long long)N_EDGES * 16;
        scatter_add<<<(int)((nwork + 255) / 256), 256, 0, stream>>>(
            (const float4*)x, ei, out);
        mlp<<<N_NODES / 4, 256, 0, stream>>>(out, W1, b1, W2, b2);
    }
}

// Round 14
// 101.166 us; speedup vs baseline: 1.0518x; 1.0340x over previous
//
#include <hip/hip_runtime.h>

#define N_NODES 100000
#define N_EDGES 1600000

// --- bucket-sort build parameters ---
#define SPAN 256
#define NB 391                        // ceil(100000/256)
#define NBLK_A 256
#define EPB (N_EDGES / NBLK_A)        // 6250

// --- legacy path parameters ---
#define SCAN_CHUNK 2048
#define SCAN_BLOCKS ((N_NODES + SCAN_CHUNK - 1) / SCAN_CHUNK)

typedef __attribute__((ext_vector_type(8))) short bf16x8;
typedef __attribute__((ext_vector_type(4))) float f32x4;

static __device__ __forceinline__ unsigned short f2bf(float f) {
    unsigned u = __float_as_uint(f);
    unsigned r = (u + 0x7FFF + ((u >> 16) & 1)) >> 16;   // RNE
    return (unsigned short)r;
}

// ===========================================================================
// Build: deterministic two-level bucket sort, no global atomics.
// ws (ints): M[NBLK_A*NB] | bcount[NB] | bbase[NB+1] | binned[E] | csr[E] | offs[N]
// bin_edges block 0 materializes bbase so bucket_sort skips its own scan.
// ===========================================================================

__global__ __launch_bounds__(512) void count_buckets(const int* __restrict__ ei,
                                                     int* __restrict__ M) {
    __shared__ int hist[NB];
    int tid = threadIdx.x;
    for (int i = tid; i < NB; i += 512) hist[i] = 0;
    __syncthreads();
    int e0 = blockIdx.x * EPB;
    for (int e = e0 + tid; e < e0 + EPB; e += 512)
        atomicAdd(&hist[ei[N_EDGES + e] >> 8], 1);
    __syncthreads();
    for (int i = tid; i < NB; i += 512) M[blockIdx.x * NB + i] = hist[i];
}

// One block per bucket: parallel LDS scan over the 256 per-block counts.
__global__ __launch_bounds__(256) void col_scan(int* __restrict__ M,
                                                int* __restrict__ bcount) {
    __shared__ int s[256];
    int b = blockIdx.x;          // bucket
    int t = threadIdx.x;         // source block
    int v = M[t * NB + b];
    s[t] = v;
    __syncthreads();
    for (int off = 1; off < 256; off <<= 1) {
        int u = (t >= off) ? s[t - off] : 0;
        __syncthreads();
        s[t] += u;
        __syncthreads();
    }
    M[t * NB + b] = s[t] - v;    // exclusive offset of block t within bucket b
    if (t == 255) bcount[b] = s[255];
}

__global__ __launch_bounds__(512) void bin_edges(const int* __restrict__ ei,
                                                 const int* __restrict__ M,
                                                 const int* __restrict__ bcount,
                                                 int* __restrict__ binned,
                                                 int* __restrict__ bbase) {
    __shared__ int sb[512];
    __shared__ int sbase[NB];
    __shared__ int cur[NB];
    int tid = threadIdx.x;

    // Bucket bases: inclusive scan of bcount over 512 lanes.
    int v = (tid < NB) ? bcount[tid] : 0;
    sb[tid] = v;
    __syncthreads();
    for (int off = 1; off < 512; off <<= 1) {
        int t = (tid >= off) ? sb[tid - off] : 0;
        __syncthreads();
        sb[tid] += t;
        __syncthreads();
    }
    if (tid < NB) {
        int gbase = sb[tid] - v;                    // global bucket base
        sbase[tid] = gbase + M[blockIdx.x * NB + tid];
        cur[tid] = 0;
        if (blockIdx.x == 0) bbase[tid] = gbase;    // materialize for bucket_sort
    }
    if (blockIdx.x == 0 && tid == NB - 1) bbase[NB] = sb[tid];
    __syncthreads();

    int e0 = blockIdx.x * EPB;
    for (int e = e0 + tid; e < e0 + EPB; e += 512) {
        int d = ei[N_EDGES + e];
        int s = ei[e];
        int b = d >> 8;
        int r = atomicAdd(&cur[b], 1);
        binned[sbase[b] + r] = (s << 8) | (d & 255);   // src:17b | local_dst:8b
    }
}

__global__ __launch_bounds__(512) void bucket_sort(const int* __restrict__ binned,
                                                   const int* __restrict__ bbase,
                                                   int* __restrict__ csr,
                                                   int* __restrict__ offs) {
    __shared__ int lh[256];
    __shared__ int ls[256];
    __shared__ int lc[256];
    int tid = threadIdx.x;
    int b = blockIdx.x;
    int base = bbase[b];              // precomputed by bin_edges (no scan here)
    int cnt = bbase[b + 1] - base;

    if (tid < 256) lh[tid] = 0;
    __syncthreads();
    for (int i = tid; i < cnt; i += 512)
        atomicAdd(&lh[binned[base + i] & 255], 1);
    __syncthreads();

    int own = 0;
    if (tid < 256) {
        own = lh[tid];
        ls[tid] = own;
    }
    __syncthreads();
    for (int off = 1; off < 256; off <<= 1) {
        int t = (tid < 256 && tid >= off) ? ls[tid - off] : 0;
        __syncthreads();
        if (tid < 256) ls[tid] += t;
        __syncthreads();
    }

    if (tid < 256) {
        int node = b * SPAN + tid;
        if (node < N_NODES) offs[node] = base + ls[tid];   // end of segment
    }

    int ex = (tid < 256) ? (ls[tid] - own) : 0;
    __syncthreads();
    if (tid < 256) {
        ls[tid] = ex;
        lc[tid] = 0;
    }
    __syncthreads();
    for (int i = tid; i < cnt; i += 512) {
        int en = binned[base + i];
        int ld = en & 255;
        int r = atomicAdd(&lc[ld], 1);
        csr[base + ls[ld] + r] = en >> 8;
    }
}

// ===========================================================================
// Fused fp32 gather-sum + MFMA bf16 2-layer MLP (round-10 proven config).
// 512 threads = 8 waves = 32 nodes/block (4 nodes/wave, two dual-node
// passes). W staged once per 32 nodes; both MFMA layers use all 8 waves.
// ===========================================================================
__global__ __launch_bounds__(512) void gather_mfma(
    const float4* __restrict__ x4, const int* __restrict__ offs,
    const int* __restrict__ csr, float* __restrict__ out,
    const float* __restrict__ W1, const float* __restrict__ b1,
    const float* __restrict__ W2, const float* __restrict__ b2) {

    __shared__ unsigned short shA[32][72];   // h  (bf16)
    __shared__ unsigned short sh1[32][72];   // relu(h@W1+b1) (bf16)
    __shared__ unsigned short W1t[64][72];   // W1^T [j][k] bf16
    __shared__ unsigned short W2t[64][72];   // W2^T [j][k] bf16

    int tid = threadIdx.x;
    int w = tid >> 6;
    int lane = tid & 63;

    // --- Stage W1^T / W2^T as bf16 (coalesced reads, b128 LDS stores) ---
    {
        int j = lane;               // output feature (row of Wt)
        int kc = w;                 // k-chunk 0..7
        unsigned p1[4], p2[4];
#pragma unroll
        for (int h = 0; h < 4; ++h) {
            float a0 = W1[(kc * 8 + 2 * h) * 64 + j];
            float a1 = W1[(kc * 8 + 2 * h + 1) * 64 + j];
            p1[h] = (unsigned)f2bf(a0) | ((unsigned)f2bf(a1) << 16);
            float c0 = W2[(kc * 8 + 2 * h) * 64 + j];
            float c1 = W2[(kc * 8 + 2 * h + 1) * 64 + j];
            p2[h] = (unsigned)f2bf(c0) | ((unsigned)f2bf(c1) << 16);
        }
        *(uint4*)&W1t[j][kc * 8] = make_uint4(p1[0], p1[1], p1[2], p1[3]);
        *(uint4*)&W2t[j][kc * 8] = make_uint4(p2[0], p2[1], p2[2], p2[3]);
    }

    // --- Gather: wave w owns nodes 4w..4w+3 of this block's 32 ---
    int s = lane >> 4;               // neighbor slot 0..3
    int c = lane & 15;               // float4 chunk 0..15
    int nodeBase = blockIdx.x * 32 + 4 * w;

#pragma unroll
    for (int g = 0; g < 2; ++g) {
        int nA = nodeBase + 2 * g;
        int nB = nA + 1;
        int stA = (nA == 0) ? 0 : offs[nA - 1];
        int enA = offs[nA];
        int stB = offs[nB - 1];
        int enB = offs[nB];

        float4 accA = make_float4(0.f, 0.f, 0.f, 0.f);
        float4 accB = accA;
        if (s == 0) {
            accA = x4[(size_t)nA * 16 + c];   // exact fp32 self term (eps=0)
            accB = x4[(size_t)nB * 16 + c];
        }

        for (int bA = stA, bB = stB; bA < enA || bB < enB; bA += 16, bB += 16) {
            int pA = bA + s, pB = bB + s;
            if (bA + 16 <= enA && bB + 16 <= enB) {
                int a0 = csr[pA], a1 = csr[pA + 4], a2 = csr[pA + 8], a3 = csr[pA + 12];
                int b0 = csr[pB], b1i = csr[pB + 4], b2i = csr[pB + 8], b3i = csr[pB + 12];
                float4 vA0 = x4[(size_t)a0 * 16 + c];
                float4 vA1 = x4[(size_t)a1 * 16 + c];
                float4 vA2 = x4[(size_t)a2 * 16 + c];
                float4 vA3 = x4[(size_t)a3 * 16 + c];
                float4 vB0 = x4[(size_t)b0 * 16 + c];
                float4 vB1 = x4[(size_t)b1i * 16 + c];
                float4 vB2 = x4[(size_t)b2i * 16 + c];
                float4 vB3 = x4[(size_t)b3i * 16 + c];
                accA.x += vA0.x + vA1.x + vA2.x + vA3.x;
                accA.y += vA0.y + vA1.y + vA2.y + vA3.y;
                accA.z += vA0.z + vA1.z + vA2.z + vA3.z;
                accA.w += vA0.w + vA1.w + vA2.w + vA3.w;
                accB.x += vB0.x + vB1.x + vB2.x + vB3.x;
                accB.y += vB0.y + vB1.y + vB2.y + vB3.y;
                accB.z += vB0.z + vB1.z + vB2.z + vB3.z;
                accB.w += vB0.w + vB1.w + vB2.w + vB3.w;
            } else {
                int a0 = (pA      < enA) ? csr[pA]      : -1;
                int a1 = (pA + 4  < enA) ? csr[pA + 4]  : -1;
                int a2 = (pA + 8  < enA) ? csr[pA + 8]  : -1;
                int a3 = (pA + 12 < enA) ? csr[pA + 12] : -1;
                int b0 = (pB      < enB) ? csr[pB]      : -1;
                int b1i = (pB + 4 < enB) ? csr[pB + 4]  : -1;
                int b2i = (pB + 8 < enB) ? csr[pB + 8]  : -1;
                int b3i = (pB + 12 < enB) ? csr[pB + 12] : -1;
                float4 vA0 = x4[(size_t)max(a0, 0) * 16 + c];
                float4 vA1 = x4[(size_t)max(a1, 0) * 16 + c];
                float4 vA2 = x4[(size_t)max(a2, 0) * 16 + c];
                float4 vA3 = x4[(size_t)max(a3, 0) * 16 + c];
                float4 vB0 = x4[(size_t)max(b0, 0) * 16 + c];
                float4 vB1 = x4[(size_t)max(b1i, 0) * 16 + c];
                float4 vB2 = x4[(size_t)max(b2i, 0) * 16 + c];
                float4 vB3 = x4[(size_t)max(b3i, 0) * 16 + c];
                if (a0 >= 0) { accA.x += vA0.x; accA.y += vA0.y; accA.z += vA0.z; accA.w += vA0.w; }
                if (a1 >= 0) { accA.x += vA1.x; accA.y += vA1.y; accA.z += vA1.z; accA.w += vA1.w; }
                if (a2 >= 0) { accA.x += vA2.x; accA.y += vA2.y; accA.z += vA2.z; accA.w += vA2.w; }
                if (a3 >= 0) { accA.x += vA3.x; accA.y += vA3.y; accA.z += vA3.z; accA.w += vA3.w; }
                if (b0 >= 0) { accB.x += vB0.x; accB.y += vB0.y; accB.z += vB0.z; accB.w += vB0.w; }
                if (b1i >= 0) { accB.x += vB1.x; accB.y += vB1.y; accB.z += vB1.z; accB.w += vB1.w; }
                if (b2i >= 0) { accB.x += vB2.x; accB.y += vB2.y; accB.z += vB2.z; accB.w += vB2.w; }
                if (b3i >= 0) { accB.x += vB3.x; accB.y += vB3.y; accB.z += vB3.z; accB.w += vB3.w; }
            }
        }

        // Reduce the 4 neighbor slots.
        accA.x += __shfl_xor(accA.x, 16); accA.y += __shfl_xor(accA.y, 16);
        accA.z += __shfl_xor(accA.z, 16); accA.w += __shfl_xor(accA.w, 16);
        accA.x += __shfl_xor(accA.x, 32); accA.y += __shfl_xor(accA.y, 32);
        accA.z += __shfl_xor(accA.z, 32); accA.w += __shfl_xor(accA.w, 32);
        accB.x += __shfl_xor(accB.x, 16); accB.y += __shfl_xor(accB.y, 16);
        accB.z += __shfl_xor(accB.z, 16); accB.w += __shfl_xor(accB.w, 16);
        accB.x += __shfl_xor(accB.x, 32); accB.y += __shfl_xor(accB.y, 32);
        accB.z += __shfl_xor(accB.z, 32); accB.w += __shfl_xor(accB.w, 32);

        if (s == 0) {
            ushort4 ra, rb;
            ra.x = f2bf(accA.x); ra.y = f2bf(accA.y);
            ra.z = f2bf(accA.z); ra.w = f2bf(accA.w);
            rb.x = f2bf(accB.x); rb.y = f2bf(accB.y);
            rb.z = f2bf(accB.z); rb.w = f2bf(accB.w);
            *(ushort4*)&shA[4 * w + 2 * g][c * 4] = ra;
            *(ushort4*)&shA[4 * w + 2 * g + 1][c * 4] = rb;
        }
    }
    __syncthreads();   // shA, W1t, W2t ready

    int row = lane & 15;
    int kg = lane >> 4;
    int rg = w >> 2;                 // row-group 0/1 (rows rg*16..rg*16+15)
    int ct = w & 3;                  // col-tile 0..3
    int jj = ct * 16 + row;          // output feature for B-frag / store

    // --- Layer 1 (all 8 waves) ---
    {
        bf16x8 a0 = *(bf16x8*)&shA[rg * 16 + row][kg * 8];
        bf16x8 a1 = *(bf16x8*)&shA[rg * 16 + row][32 + kg * 8];
        bf16x8 w0 = *(bf16x8*)&W1t[jj][kg * 8];
        bf16x8 w1 = *(bf16x8*)&W1t[jj][32 + kg * 8];
        f32x4 d = {0.f, 0.f, 0.f, 0.f};
        d = __builtin_amdgcn_mfma_f32_16x16x32_bf16(a0, w0, d, 0, 0, 0);
        d = __builtin_amdgcn_mfma_f32_16x16x32_bf16(a1, w1, d, 0, 0, 0);
        float bias = b1[jj];
#pragma unroll
        for (int i = 0; i < 4; ++i) {
            float v = fmaxf(d[i] + bias, 0.f);
            sh1[rg * 16 + kg * 4 + i][jj] = f2bf(v);
        }
    }

    // Preload layer-2 weight fragments before the barrier.
    bf16x8 w20 = *(bf16x8*)&W2t[jj][kg * 8];
    bf16x8 w21 = *(bf16x8*)&W2t[jj][32 + kg * 8];
    __syncthreads();   // sh1 ready

    // --- Layer 2 (all 8 waves) + store ---
    {
        bf16x8 a0 = *(bf16x8*)&sh1[rg * 16 + row][kg * 8];
        bf16x8 a1 = *(bf16x8*)&sh1[rg * 16 + row][32 + kg * 8];
        f32x4 d = {0.f, 0.f, 0.f, 0.f};
        d = __builtin_amdgcn_mfma_f32_16x16x32_bf16(a0, w20, d, 0, 0, 0);
        d = __builtin_amdgcn_mfma_f32_16x16x32_bf16(a1, w21, d, 0, 0, 0);
        float bias = b2[jj];
        int nbase = blockIdx.x * 32 + rg * 16 + kg * 4;
#pragma unroll
        for (int i = 0; i < 4; ++i)
            out[(size_t)(nbase + i) * 64 + jj] = d[i] + bias;
    }
}

// ===========================================================================
// Round-5 fp32-gather + VALU MLP kernel (mid fallback).
// ===========================================================================
__global__ __launch_bounds__(512) void gather_mlp(
    const float4* __restrict__ x4, const int* __restrict__ offs,
    const int* __restrict__ csr, float* __restrict__ out,
    const float* __restrict__ W1, const float* __restrict__ b1,
    const float* __restrict__ W2, const float* __restrict__ b2) {
    __shared__ float sW1[64][64];
    __shared__ float sW2[64][64];
    __shared__ float sb1[64];
    __shared__ float sb2[64];
    __shared__ float sh[8][64];
    __shared__ float sh1[8][64];

    int tid = threadIdx.x;
    for (int i = tid; i < 4096; i += 512) {
        sW1[i >> 6][i & 63] = W1[i];
        sW2[i >> 6][i & 63] = W2[i];
    }
    if (tid < 64) {
        sb1[tid] = b1[tid];
        sb2[tid] = b2[tid];
    }

    int local = tid >> 6;
    int lane = tid & 63;
    int s = lane >> 4;
    int c = lane & 15;
    int node = blockIdx.x * 8 + local;

    int start = (node == 0) ? 0 : offs[node - 1];
    int end = offs[node];

    float4 acc = make_float4(0.f, 0.f, 0.f, 0.f);
    float4 self = x4[(size_t)node * 16 + c];
    if (s == 0) acc = self;

    for (int b = start; b < end; b += 16) {
        int p = b + s;
        int i0 = (p < end) ? csr[p] : -1;
        int i1 = (p + 4 < end) ? csr[p + 4] : -1;
        int i2 = (p + 8 < end) ? csr[p + 8] : -1;
        int i3 = (p + 12 < end) ? csr[p + 12] : -1;
        float4 v0 = x4[(size_t)max(i0, 0) * 16 + c];
        float4 v1 = x4[(size_t)max(i1, 0) * 16 + c];
        float4 v2 = x4[(size_t)max(i2, 0) * 16 + c];
        float4 v3 = x4[(size_t)max(i3, 0) * 16 + c];
        if (i0 >= 0) { acc.x += v0.x; acc.y += v0.y; acc.z += v0.z; acc.w += v0.w; }
        if (i1 >= 0) { acc.x += v1.x; acc.y += v1.y; acc.z += v1.z; acc.w += v1.w; }
        if (i2 >= 0) { acc.x += v2.x; acc.y += v2.y; acc.z += v2.z; acc.w += v2.w; }
        if (i3 >= 0) { acc.x += v3.x; acc.y += v3.y; acc.z += v3.z; acc.w += v3.w; }
    }

    acc.x += __shfl_xor(acc.x, 16); acc.y += __shfl_xor(acc.y, 16);
    acc.z += __shfl_xor(acc.z, 16); acc.w += __shfl_xor(acc.w, 16);
    acc.x += __shfl_xor(acc.x, 32); acc.y += __shfl_xor(acc.y, 32);
    acc.z += __shfl_xor(acc.z, 32); acc.w += __shfl_xor(acc.w, 32);

    __syncthreads();
    if (s == 0) *(float4*)&sh[local][c * 4] = acc;
    __syncthreads();

    int j = lane;
    float a1 = sb1[j];
#pragma unroll
    for (int k = 0; k < 64; ++k) a1 = fmaf(sh[local][k], sW1[k][j], a1);
    a1 = fmaxf(a1, 0.0f);
    sh1[local][j] = a1;
    __syncthreads();

    float a2 = sb2[j];
#pragma unroll
    for (int k = 0; k < 64; ++k) a2 = fmaf(sh1[local][k], sW2[k][j], a2);
    out[(size_t)node * 64 + j] = a2;
}

// ===========================================================================
// Legacy scan build + atomic fallback (unchanged).
// ===========================================================================
__global__ void zero_ints(int* __restrict__ p, int n) {
    int i = blockIdx.x * blockDim.x + threadIdx.x;
    if (i < n) p[i] = 0;
}

__global__ void count_deg(const int* __restrict__ ei, int* __restrict__ deg) {
    int e = blockIdx.x * blockDim.x + threadIdx.x;
    if (e < N_EDGES) atomicAdd(&deg[ei[N_EDGES + e]], 1);
}

__global__ __launch_bounds__(256) void scan_a(const int* __restrict__ deg,
                                              int* __restrict__ offs,
                                              int* __restrict__ bsum) {
    __shared__ int lds[256];
    int tid = threadIdx.x;
    int base = blockIdx.x * SCAN_CHUNK + tid * 8;
    int v[8], ex[8];
    int run = 0;
#pragma unroll
    for (int k = 0; k < 8; ++k) {
        v[k] = (base + k < N_NODES) ? deg[base + k] : 0;
        ex[k] = run;
        run += v[k];
    }
    lds[tid] = run;
    __syncthreads();
    for (int off = 1; off < 256; off <<= 1) {
        int t = (tid >= off) ? lds[tid - off] : 0;
        __syncthreads();
        lds[tid] += t;
        __syncthreads();
    }
    int prefix = lds[tid] - run;
#pragma unroll
    for (int k = 0; k < 8; ++k)
        if (base + k < N_NODES) offs[base + k] = prefix + ex[k];
    if (tid == 0) bsum[blockIdx.x] = lds[255];
}

__global__ void scan_c(int* __restrict__ offs, const int* __restrict__ bsum) {
    int i = blockIdx.x * blockDim.x + threadIdx.x;
    if (i >= N_NODES) return;
    int chunk = i / SCAN_CHUNK;
    int add = 0;
    for (int t = 0; t < chunk; ++t) add += bsum[t];
    offs[i] += add;
}

__global__ void fill_csr(const int* __restrict__ ei, int* __restrict__ offs,
                         int* __restrict__ csr) {
    int e = blockIdx.x * blockDim.x + threadIdx.x;
    if (e >= N_EDGES) return;
    int src = ei[e];
    int dst = ei[N_EDGES + e];
    int pos = atomicAdd(&offs[dst], 1);
    csr[pos] = src;
}

__global__ void init_h(const float4* __restrict__ x, float4* __restrict__ h,
                       int n4) {
    int i = blockIdx.x * blockDim.x + threadIdx.x;
    if (i < n4) h[i] = x[i];
}

__global__ void scatter_add(const float4* __restrict__ x4,
                            const int* __restrict__ ei,
                            float* __restrict__ h) {
    long long i = (long long)blockIdx.x * blockDim.x + threadIdx.x;
    if (i >= (long long)N_EDGES * 16) return;
    int e = (int)(i >> 4);
    int lane = (int)(i & 15);
    int src = ei[e];
    int dst = ei[N_EDGES + e];
    float4 v = x4[(long long)src * 16 + lane];
    float* p = h + (long long)dst * 64 + lane * 4;
    unsafeAtomicAdd(p + 0, v.x);
    unsafeAtomicAdd(p + 1, v.y);
    unsafeAtomicAdd(p + 2, v.z);
    unsafeAtomicAdd(p + 3, v.w);
}

__global__ __launch_bounds__(256) void mlp(float* __restrict__ h,
                                           const float* __restrict__ W1,
                                           const float* __restrict__ b1,
                                           const float* __restrict__ W2,
                                           const float* __restrict__ b2) {
    __shared__ float sW1[64][64];
    __shared__ float sW2[64][64];
    __shared__ float sb1[64];
    __shared__ float sb2[64];
    __shared__ float sh[4][64];
    __shared__ float sh1[4][64];
    int tid = threadIdx.x;
    for (int i = tid; i < 4096; i += 256) {
        sW1[i >> 6][i & 63] = W1[i];
        sW2[i >> 6][i & 63] = W2[i];
    }
    if (tid < 64) { sb1[tid] = b1[tid]; sb2[tid] = b2[tid]; }
    __syncthreads();
    int local = tid >> 6, j = tid & 63;
    int node = blockIdx.x * 4 + local;
    sh[local][j] = h[(long long)node * 64 + j];
    __syncthreads();
    float acc = sb1[j];
#pragma unroll
    for (int k = 0; k < 64; ++k) acc = fmaf(sh[local][k], sW1[k][j], acc);
    acc = fmaxf(acc, 0.0f);
    sh1[local][j] = acc;
    __syncthreads();
    float acc2 = sb2[j];
#pragma unroll
    for (int k = 0; k < 64; ++k) acc2 = fmaf(sh1[local][k], sW2[k][j], acc2);
    h[(long long)node * 64 + j] = acc2;
}

extern "C" void kernel_launch(void* const* d_in, const int* in_sizes, int n_in,
                              void* d_out, int out_size, void* d_ws, size_t ws_size,
                              hipStream_t stream) {
    const float* x = (const float*)d_in[0];
    const int* ei = (const int*)d_in[1];   // harness stores ints as int32
    const float* W1 = (const float*)d_in[2];
    const float* b1 = (const float*)d_in[3];
    const float* W2 = (const float*)d_in[4];
    const float* b2 = (const float*)d_in[5];
    float* out = (float*)d_out;

    size_t need_csr = (size_t)(N_NODES + NBLK_A * NB + NB + (NB + 1) +
                               2 * N_EDGES) * sizeof(int);
    size_t need_mid = (size_t)(2 * N_NODES + SCAN_BLOCKS + N_EDGES) * sizeof(int);

    if (ws_size >= need_csr) {
        int* offs = (int*)d_ws;
        int* M = offs + N_NODES;
        int* bcount = M + NBLK_A * NB;
        int* bbase = bcount + NB;
        int* binned = bbase + (NB + 1);
        int* csr = binned + N_EDGES;

        count_buckets<<<NBLK_A, 512, 0, stream>>>(ei, M);
        col_scan<<<NB, 256, 0, stream>>>(M, bcount);
        bin_edges<<<NBLK_A, 512, 0, stream>>>(ei, M, bcount, binned, bbase);
        bucket_sort<<<NB, 512, 0, stream>>>(binned, bbase, csr, offs);
        gather_mfma<<<N_NODES / 32, 512, 0, stream>>>((const float4*)x, offs,
                                                      csr, out, W1, b1, W2, b2);
    } else if (ws_size >= need_mid) {
        int* deg = (int*)d_ws;
        int* offs = deg + N_NODES;
        int* bsum = offs + N_NODES;
        int* csr = bsum + SCAN_BLOCKS;

        zero_ints<<<(N_NODES + 255) / 256, 256, 0, stream>>>(deg, N_NODES);
        count_deg<<<(N_EDGES + 255) / 256, 256, 0, stream>>>(ei, deg);
        scan_a<<<SCAN_BLOCKS, 256, 0, stream>>>(deg, offs, bsum);
        scan_c<<<(N_NODES + 255) / 256, 256, 0, stream>>>(offs, bsum);
        fill_csr<<<(N_EDGES + 255) / 256, 256, 0, stream>>>(ei, offs, csr);
        gather_mlp<<<N_NODES / 8, 512, 0, stream>>>((const float4*)x, offs,
                                                    csr, out, W1, b1, W2, b2);
    } else {
        int n4 = N_NODES * 64 / 4;
        init_h<<<(n4 + 255) / 256, 256, 0, stream>>>((const float4*)x,
                                                     (float4*)out, n4);
        long long nwork = (long long)N_EDGES * 16;
        scatter_add<<<(int)((nwork + 255) / 256), 256, 0, stream>>>(
            (const float4*)x, ei, out);
        mlp<<<N_NODES / 4, 256, 0, stream>>>(out, W1, b1, W2, b2);
    }
}